// Round 7
// baseline (1059.589 us; speedup 1.0000x reference)
//
#include <hip/hip_runtime.h>
#include <math.h>

// Problem constants (fixed by setup_inputs)
#define BB 4
#define HH 128
#define DD 512
#define WW 512
#define GG 72
#define PP 65536
#define CHUNK 256
#define NCHUNK (PP / CHUNK)          // 256
#define HDW (HH * DD * WW)           // 33,554,432
#define NBRICK (HDW / 8)             // 4,194,304 bricks of 2x2x2 voxels
#define CPB 2                        // chunks per density block (2 = measured optimum)
#define NPART (NCHUNK / CPB)         // 128 dist partials per g (fast path)

typedef _Float16 half4 __attribute__((ext_vector_type(4)));
typedef _Float16 half8 __attribute__((ext_vector_type(8)));
typedef float f4 __attribute__((ext_vector_type(4)));   // NT-load-compatible

// ---------------------------------------------------------------------------
// Transpose + quantize into 64B bricks (one brick = 2x2x2 voxels x 4 batches
// fp16 = 64 B = 1 cache line; 2x2x2 is the line-footprint optimum: E[lines
// per trilinear stencil] = 1.5^3 = 3.375). NT reads keep the 512 MiB ct
// stream from evicting the tv writes from L3 — density depends on tv
// being L3-resident.
// ---------------------------------------------------------------------------
__global__ __launch_bounds__(256) void k_transpose(
    const float* __restrict__ ct, _Float16* __restrict__ tv)
{
    const int n2  = blockIdx.x * 256 + threadIdx.x;  // brick-pair index
    const int bxp = n2 & 127;                        // 128 pairs per x-row
    const int by  = (n2 >> 7) & 255;                 // DD/2
    const int bz  = n2 >> 15;                        // HH/2
    const size_t base = ((size_t)(2 * bz) * DD + 2 * by) * WW + 4 * bxp;

    half8 o00, o01, o02, o03;   // brick 0: inner pairs (oz,oy) = 00,01,10,11
    half8 o10, o11, o12, o13;   // brick 1
#pragma unroll
    for (int b = 0; b < BB; ++b) {
        const float* v = ct + (size_t)b * HDW + base;
        const f4 f00 = __builtin_nontemporal_load((const f4*)(v));
        const f4 f01 = __builtin_nontemporal_load((const f4*)(v + WW));
        const f4 f10 = __builtin_nontemporal_load((const f4*)(v + (size_t)DD * WW));
        const f4 f11 = __builtin_nontemporal_load((const f4*)(v + (size_t)DD * WW + WW));
        o00[b] = (_Float16)f00[0]; o00[4 + b] = (_Float16)f00[1];
        o01[b] = (_Float16)f01[0]; o01[4 + b] = (_Float16)f01[1];
        o02[b] = (_Float16)f10[0]; o02[4 + b] = (_Float16)f10[1];
        o03[b] = (_Float16)f11[0]; o03[4 + b] = (_Float16)f11[1];
        o10[b] = (_Float16)f00[2]; o10[4 + b] = (_Float16)f00[3];
        o11[b] = (_Float16)f01[2]; o11[4 + b] = (_Float16)f01[3];
        o12[b] = (_Float16)f10[2]; o12[4 + b] = (_Float16)f10[3];
        o13[b] = (_Float16)f11[2]; o13[4 + b] = (_Float16)f11[3];
    }
    _Float16* dst = tv + (size_t)n2 * 64;   // two consecutive 64 B bricks
    *(half8*)(dst)      = o00;
    *(half8*)(dst + 8)  = o01;
    *(half8*)(dst + 16) = o02;
    *(half8*)(dst + 24) = o03;
    *(half8*)(dst + 32) = o10;
    *(half8*)(dst + 40) = o11;
    *(half8*)(dst + 48) = o12;
    *(half8*)(dst + 56) = o13;
}

// half-element offset of corner voxel (zc,yc,xc) in the brick volume
__device__ __forceinline__ int brick_off(int zc, int yc, int xc)
{
    const int brick = ((zc >> 1) << 16) | ((yc >> 1) << 8) | (xc >> 1);
    const int inner = ((zc & 1) << 2) | ((yc & 1) << 1) | (xc & 1);
    return (brick << 5) | (inner << 2);
}

struct PS {
    int i[8];
    float xd, yd, zd;
};

__device__ __forceinline__ PS setup_brick(float cx, float cy, float cz)
{
    const float x = fminf(fmaxf(cx, 0.0f), (float)(WW - 1));
    const float y = fminf(fmaxf(cy, 0.0f), (float)(DD - 1));
    const float z = fminf(fmaxf(cz, 0.0f), (float)(HH - 1));
    const int x0 = (int)floorf(x);
    const int y0 = (int)floorf(y);
    const int z0 = (int)floorf(z);
    const int x1 = min(x0 + 1, WW - 1);
    const int y1 = min(y0 + 1, DD - 1);
    const int z1 = min(z0 + 1, HH - 1);
    PS s;
    s.xd = x - (float)x0;
    s.yd = y - (float)y0;
    s.zd = z - (float)z0;
    s.i[0] = brick_off(z0, y0, x0); s.i[1] = brick_off(z0, y0, x1);
    s.i[2] = brick_off(z0, y1, x0); s.i[3] = brick_off(z0, y1, x1);
    s.i[4] = brick_off(z1, y0, x0); s.i[5] = brick_off(z1, y0, x1);
    s.i[6] = brick_off(z1, y1, x0); s.i[7] = brick_off(z1, y1, x1);
    return s;
}

__device__ __forceinline__ void gather8(
    const _Float16* __restrict__ tv, const PS& s, half4 A[8])
{
#pragma unroll
    for (int k = 0; k < 8; ++k) A[k] = *(const half4*)(tv + (size_t)s.i[k]);
}

__device__ __forceinline__ void lerp8(
    const half4 A[8], float xd, float yd, float zd, float dens[BB])
{
#pragma unroll
    for (int b = 0; b < BB; ++b) {
        const float c000 = (float)A[0][b], c001 = (float)A[1][b];
        const float c010 = (float)A[2][b], c011 = (float)A[3][b];
        const float c100 = (float)A[4][b], c101 = (float)A[5][b];
        const float c110 = (float)A[6][b], c111 = (float)A[7][b];
        const float c00 = c000 * (1.0f - xd) + c001 * xd;
        const float c01 = c010 * (1.0f - xd) + c011 * xd;
        const float c10 = c100 * (1.0f - xd) + c101 * xd;
        const float c11 = c110 * (1.0f - xd) + c111 * xd;
        const float c0  = c00 * (1.0f - yd) + c01 * yd;
        const float c1  = c10 * (1.0f - yd) + c11 * yd;
        dens[b] = c0 * (1.0f - zd) + c1 * zd;
    }
}

// ---------------------------------------------------------------------------
// Density kernel, single pass, 2 chunks per block (2 points per thread,
// 16 outstanding gathers). __launch_bounds__(256,8) caps VGPR at 64 to hold
// 8 waves/SIMD: round-5's CPB=4 regression proved the kernel is latency-
// exposed, so occupancy is the hiding mechanism. gather8(A0) is issued
// before s1 is built so s0.i dies early (liveness ~54 regs at peak).
// NEW: the intra-chunk inclusive scan is done HERE (on the VALU that idles
// under the gathers) — it replaces the old block reduction at the same
// shuffle count, the chunk totals fall out of the wave-totals, and density
// is written ALREADY SCANNED so k_output needs no scan chain.
// grid = (NCHUNK/2, GG), block = 256.
// ---------------------------------------------------------------------------
__global__ __launch_bounds__(256, 8) void k_density_h(
    const _Float16* __restrict__ tv,    // brick volume fp16
    const float* __restrict__ coords,   // [G, P, 3]
    float* __restrict__ density,        // [B*G, P] — INCLUSIVE-SCANNED per chunk
    float* __restrict__ chunk_sums,     // [B*G, NCHUNK]
    float* __restrict__ dist_part)      // [G, NPART]
{
    const int cpair = blockIdx.x;            // handles chunks c0, c0+1
    const int g     = blockIdx.y;
    const int t     = threadIdx.x;
    const int c0    = cpair * CPB;
    const int p0    = c0 * CHUNK + t;        // p1 = p0 + 256

    __shared__ float cbuf[(CPB * CHUNK + 1) * 3];
    const bool last  = (cpair == NPART - 1);
    const int  nload = last ? CPB * CHUNK * 3 : (CPB * CHUNK + 1) * 3;
    const float* src = coords + ((size_t)g * PP + (size_t)c0 * CHUNK) * 3;
    for (int i = t; i < nload; i += 256)
        cbuf[i] = __builtin_nontemporal_load(src + i);
    __syncthreads();

    const float ax = cbuf[3 * t + 0], ay = cbuf[3 * t + 1], az = cbuf[3 * t + 2];
    const int   u  = t + 256;
    const float bx = cbuf[3 * u + 0], by = cbuf[3 * u + 1], bz = cbuf[3 * u + 2];

    float dist_tot;
    {
        const float dx = cbuf[3 * (t + 1) + 0] - ax;
        const float dy = cbuf[3 * (t + 1) + 1] - ay;
        const float dz = cbuf[3 * (t + 1) + 2] - az;
        dist_tot = sqrtf(dx * dx + dy * dy + dz * dz);   // p0 <= 65279 always
    }
    if (!(last && t == CHUNK - 1)) {
        const float dx = cbuf[3 * (u + 1) + 0] - bx;
        const float dy = cbuf[3 * (u + 1) + 1] - by;
        const float dz = cbuf[3 * (u + 1) + 2] - bz;
        dist_tot += sqrtf(dx * dx + dy * dy + dz * dz);
    }

    // Setup + issue point 0's gathers first so s0.i[] dies before s1 exists.
    half4 A0[8], A1[8];
    const PS s0 = setup_brick(ax, ay, az);
    gather8(tv, s0, A0);
    const PS s1 = setup_brick(bx, by, bz);
    gather8(tv, s1, A1);

    float v0[BB], v1[BB];
    lerp8(A0, s0.xd, s0.yd, s0.zd, v0);
    lerp8(A1, s1.xd, s1.yd, s1.zd, v1);

    // Intra-chunk inclusive scan (per chunk, across the 256-thread block).
    const int lane = t & 63;
    const int wid  = t >> 6;
#pragma unroll
    for (int d = 1; d < 64; d <<= 1) {
#pragma unroll
        for (int b = 0; b < BB; ++b) {
            const float n0 = __shfl_up(v0[b], d);
            const float n1 = __shfl_up(v1[b], d);
            if (lane >= d) { v0[b] += n0; v1[b] += n1; }
        }
    }
    float rd = dist_tot;
#pragma unroll
    for (int off = 32; off > 0; off >>= 1) rd += __shfl_xor(rd, off);

    __shared__ float wtot[4][9];     // per-wave: 4 v0-totals, 4 v1-totals, dist
    if (lane == 63) {
#pragma unroll
        for (int b = 0; b < BB; ++b) { wtot[wid][b] = v0[b]; wtot[wid][4 + b] = v1[b]; }
    }
    if (lane == 0) wtot[wid][8] = rd;
    __syncthreads();

    // add earlier-wave prefixes, then store the scanned values (NT)
#pragma unroll
    for (int b = 0; b < BB; ++b) {
        float pre0 = 0.0f, pre1 = 0.0f;
        for (int w = 0; w < wid; ++w) { pre0 += wtot[w][b]; pre1 += wtot[w][4 + b]; }
        __builtin_nontemporal_store(v0[b] + pre0,
            density + ((size_t)(b * GG + g)) * PP + p0);
        __builtin_nontemporal_store(v1[b] + pre1,
            density + ((size_t)(b * GG + g)) * PP + p0 + 256);
    }

    if (t == 0) {
#pragma unroll
        for (int b = 0; b < BB; ++b) {
            chunk_sums[((size_t)(b * GG + g)) * NCHUNK + c0] =
                wtot[0][b] + wtot[1][b] + wtot[2][b] + wtot[3][b];
            chunk_sums[((size_t)(b * GG + g)) * NCHUNK + c0 + 1] =
                wtot[0][4 + b] + wtot[1][4 + b] + wtot[2][4 + b] + wtot[3][4 + b];
        }
        dist_part[g * NPART + cpair] = wtot[0][8] + wtot[1][8] + wtot[2][8] + wtot[3][8];
    }
}

// ---------------------------------------------------------------------------
// Fallback density kernel (fp32 direct gather) — used if ws too small.
// Same contract: writes INCLUSIVE-SCANNED density per chunk.
// ---------------------------------------------------------------------------
__global__ __launch_bounds__(256) void k_density(
    const float* __restrict__ ct,
    const float* __restrict__ coords,
    float* __restrict__ density,
    float* __restrict__ chunk_sums,
    float* __restrict__ dist_part)      // [G, NCHUNK]
{
    const int chunk = blockIdx.x;
    const int g     = blockIdx.y;
    const int t     = threadIdx.x;
    const int p     = chunk * CHUNK + t;

    __shared__ float cbuf[(CHUNK + 1) * 3];
    const int nload = (chunk == NCHUNK - 1) ? CHUNK * 3 : (CHUNK + 1) * 3;
    const float* src = coords + ((size_t)g * PP + (size_t)chunk * CHUNK) * 3;
    for (int i = t; i < nload; i += CHUNK) cbuf[i] = src[i];
    __syncthreads();

    const float cx = cbuf[3 * t + 0];
    const float cy = cbuf[3 * t + 1];
    const float cz = cbuf[3 * t + 2];

    float dist = 0.0f;
    if (p < PP - 1) {
        const int nt = 3 * (t + 1);
        const float dx = cbuf[nt + 0] - cx;
        const float dy = cbuf[nt + 1] - cy;
        const float dz = cbuf[nt + 2] - cz;
        dist = sqrtf(dx * dx + dy * dy + dz * dz);
    }

    const float x = fminf(fmaxf(cx, 0.0f), (float)(WW - 1));
    const float y = fminf(fmaxf(cy, 0.0f), (float)(DD - 1));
    const float z = fminf(fmaxf(cz, 0.0f), (float)(HH - 1));
    const int x0 = (int)floorf(x);
    const int y0 = (int)floorf(y);
    const int z0 = (int)floorf(z);
    const int x1 = min(x0 + 1, WW - 1);
    const int y1 = min(y0 + 1, DD - 1);
    const int z1 = min(z0 + 1, HH - 1);
    const float xd = x - (float)x0, yd = y - (float)y0, zd = z - (float)z0;

    const int b00 = (z0 * DD + y0) * WW;
    const int b01 = (z0 * DD + y1) * WW;
    const int b10 = (z1 * DD + y0) * WW;
    const int b11 = (z1 * DD + y1) * WW;

    float v[BB];
#pragma unroll
    for (int b = 0; b < BB; ++b) {
        const float* vp = ct + (size_t)b * HDW;
        const float c000 = vp[b00 + x0], c001 = vp[b00 + x1];
        const float c010 = vp[b01 + x0], c011 = vp[b01 + x1];
        const float c100 = vp[b10 + x0], c101 = vp[b10 + x1];
        const float c110 = vp[b11 + x0], c111 = vp[b11 + x1];
        const float c00 = c000 * (1.0f - xd) + c001 * xd;
        const float c01 = c010 * (1.0f - xd) + c011 * xd;
        const float c10 = c100 * (1.0f - xd) + c101 * xd;
        const float c11 = c110 * (1.0f - xd) + c111 * xd;
        const float c0  = c00 * (1.0f - yd) + c01 * yd;
        const float c1  = c10 * (1.0f - yd) + c11 * yd;
        v[b] = c0 * (1.0f - zd) + c1 * zd;
    }

    const int lane = t & 63;
    const int wid  = t >> 6;
#pragma unroll
    for (int d = 1; d < 64; d <<= 1) {
#pragma unroll
        for (int b = 0; b < BB; ++b) {
            const float n = __shfl_up(v[b], d);
            if (lane >= d) v[b] += n;
        }
    }
    float rd = dist;
#pragma unroll
    for (int off = 32; off > 0; off >>= 1) rd += __shfl_xor(rd, off);

    __shared__ float wtot[4][5];
    if (lane == 63) {
#pragma unroll
        for (int b = 0; b < BB; ++b) wtot[wid][b] = v[b];
    }
    if (lane == 0) wtot[wid][4] = rd;
    __syncthreads();

#pragma unroll
    for (int b = 0; b < BB; ++b) {
        float pre = 0.0f;
        for (int w = 0; w < wid; ++w) pre += wtot[w][b];
        density[((size_t)(b * GG + g)) * PP + p] = v[b] + pre;
    }
    if (t == 0) {
#pragma unroll
        for (int b = 0; b < BB; ++b)
            chunk_sums[((size_t)(b * GG + g)) * NCHUNK + chunk] =
                wtot[0][b] + wtot[1][b] + wtot[2][b] + wtot[3][b];
        dist_part[g * NCHUNK + chunk] =
            wtot[0][4] + wtot[1][4] + wtot[2][4] + wtot[3][4];
    }
}

// ---------------------------------------------------------------------------
// Final kernel: density arrives ALREADY chunk-scanned. Per-block exclusive
// chunk prefix (masked reduction over L2-resident chunk_sums) + dist total;
// own density recovered via one shfl_up + wave-edge LDS. No scan chain.
// grid = (NCHUNK, GG), block = 256. npart = dist partials per g.
// ---------------------------------------------------------------------------
__global__ __launch_bounds__(256) void k_output(
    float* __restrict__ out,
    const float* __restrict__ cs,
    const float* __restrict__ dist_part,
    int npart)
{
    const int chunk = blockIdx.x;
    const int g     = blockIdx.y;
    const int t     = threadIdx.x;
    const int p     = chunk * CHUNK + t;
    const int lane  = t & 63;
    const int wid   = t >> 6;

    // issue the scanned-density loads first so they overlap the reductions
    float v[BB];
#pragma unroll
    for (int b = 0; b < BB; ++b)
        v[b] = __builtin_nontemporal_load(out + ((size_t)(b * GG + g)) * PP + p);

    __shared__ float exl[4];
    __shared__ float sdist;
    __shared__ float edge[4][BB];

    // wave `wid` computes the exclusive chunk prefix for batch b = wid
    {
        const float* row = cs + ((size_t)(wid * GG + g)) * NCHUNK;
        float pv = 0.0f;
#pragma unroll
        for (int k = 0; k < 4; ++k) {
            const int idx = lane + 64 * k;
            const float x = row[idx];
            pv += (idx < chunk) ? x : 0.0f;
        }
#pragma unroll
        for (int off = 32; off > 0; off >>= 1) pv += __shfl_xor(pv, off);
        if (lane == 0) exl[wid] = pv;
    }
    // wave 0 additionally sums the dist partials for g
    if (wid == 0) {
        float dv = 0.0f;
#pragma unroll
        for (int k = 0; k < 4; ++k) {
            const int idx = lane + 64 * k;
            dv += (idx < npart) ? dist_part[g * npart + idx] : 0.0f;
        }
#pragma unroll
        for (int off = 32; off > 0; off >>= 1) dv += __shfl_xor(dv, off);
        if (lane == 0) sdist = dv;
    }

    if (lane == 63) {
#pragma unroll
        for (int b = 0; b < BB; ++b) edge[wid][b] = v[b];
    }
    __syncthreads();

    const float step = sdist * (2.0f / (float)(PP - 1));
#pragma unroll
    for (int b = 0; b < BB; ++b) {
        const float n    = __shfl_up(v[b], 1);
        const float prev = (lane > 0) ? n : (wid > 0 ? edge[wid - 1][b] : 0.0f);
        const float d    = v[b] - prev;              // own density, reconstructed
        __builtin_nontemporal_store(step * (exl[b] + v[b] + 0.5f * d),
            out + ((size_t)(b * GG + g)) * PP + p);
    }
}

// ---------------------------------------------------------------------------
extern "C" void kernel_launch(void* const* d_in, const int* in_sizes, int n_in,
                              void* d_out, int out_size, void* d_ws, size_t ws_size,
                              hipStream_t stream)
{
    const float* ct     = (const float*)d_in[0];
    const float* coords = (const float*)d_in[1];
    float* out = (float*)d_out;

    const size_t volBytes = (size_t)HDW * BB * sizeof(_Float16);        // 256 MiB
    const size_t csCount  = (size_t)BB * GG * NCHUNK;
    const size_t dpCount  = (size_t)GG * NCHUNK;    // max of both paths
    const size_t needed   = volBytes + (csCount + dpCount) * sizeof(float);

    if (ws_size >= needed) {
        _Float16* tv       = (_Float16*)d_ws;
        float* chunk_sums  = (float*)((char*)d_ws + volBytes);
        float* dist_part   = chunk_sums + csCount;

        k_transpose<<<NBRICK / 2 / 256, 256, 0, stream>>>(ct, tv);
        k_density_h<<<dim3(NCHUNK / CPB, GG), 256, 0, stream>>>(tv, coords, out, chunk_sums, dist_part);
        k_output<<<dim3(NCHUNK, GG), 256, 0, stream>>>(out, chunk_sums, dist_part, NPART);
    } else {
        float* chunk_sums  = (float*)d_ws;
        float* dist_part   = chunk_sums + csCount;

        k_density<<<dim3(NCHUNK, GG), 256, 0, stream>>>(ct, coords, out, chunk_sums, dist_part);
        k_output<<<dim3(NCHUNK, GG), 256, 0, stream>>>(out, chunk_sums, dist_part, NCHUNK);
    }
}